// Round 14
// baseline (127.290 us; speedup 1.0000x reference)
//
#include <hip/hip_runtime.h>
#include <stdint.h>

// ---------------- problem constants ----------------
static constexpr int kH  = 2048;
static constexpr int kW  = 4096;
static constexpr int kHW = kH * kW;            // per-channel pixels (2^23)
static constexpr int kNH = kH / 64;   // 32
static constexpr int kNW = kW / 64;   // 64
static constexpr int kNB = kNH * kNW; // 2048 blocks
static constexpr int kBB = 64 * 64;   // 4096 pixels / block
static constexpr float kGray = 128.0f;

// partitionable threefry (JAX >= 0.4.36 default) -- validated absmax 0.0 rounds 1-13
__host__ __device__ inline void tf2x32(uint32_t k0, uint32_t k1,
                                       uint32_t x0, uint32_t x1,
                                       uint32_t& o0, uint32_t& o1) {
  uint32_t ks2 = 0x1BD11BDAu ^ k0 ^ k1;
  x0 += k0; x1 += k1;
#define ROTL(v, d) (((v) << (d)) | ((v) >> (32 - (d))))
#define RND(R) { x0 += x1; x1 = ROTL(x1, R); x1 ^= x0; }
  RND(13) RND(15) RND(26) RND(6)
  x0 += k1;  x1 += ks2 + 1u;
  RND(17) RND(29) RND(16) RND(24)
  x0 += ks2; x1 += k0 + 2u;
  RND(13) RND(15) RND(26) RND(6)
  x0 += k0;  x1 += k1 + 3u;
  RND(17) RND(29) RND(16) RND(24)
  x0 += k1;  x1 += ks2 + 4u;
  RND(13) RND(15) RND(26) RND(6)
  x0 += ks2; x1 += k0 + 5u;
  o0 = x0; o1 = x1;
#undef RND
#undef ROTL
}

__device__ inline uint32_t rbits(uint32_t ka, uint32_t kb, uint32_t idx) {
  uint32_t o0, o1;
  tf2x32(ka, kb, 0u, idx, o0, o1);
  return o0 ^ o1;
}

__device__ inline bool keep_block(uint32_t k1a, uint32_t k1b, int b) {
  uint32_t v = rbits(k1a, k1b, (uint32_t)b) >> 9;
  return v > 0x400000u;   // uniform > 0.5 exactly
}

// ---------------- K1 (R13-validated): depth max + block-local gray ----------------
__global__ __launch_bounds__(256) void k1_depth(const float* __restrict__ depth,
                                                float* __restrict__ out,
                                                float* __restrict__ Bmax,
                                                uint32_t k1a, uint32_t k1b_) {
  __shared__ float red[256];
  const int b = blockIdx.x, t = threadIdx.x;
  const int bi = b >> 6, bj = b & 63;
  const int y0 = bi * 64, x0 = bj * 64;
  const bool keep = keep_block(k1a, k1b_, b);
  const float4* d4 = reinterpret_cast<const float4*>(depth);
  float4* out4 = reinterpret_cast<float4*>(out);

  float mx = 0.0f;
  #pragma unroll
  for (int it = 0; it < 4; ++it) {
    int idx = it * 256 + t;
    int r = idx >> 4, cq = idx & 15;
    uint32_t a4 = (uint32_t)(y0 + r) * (kW / 4) + (uint32_t)(x0 / 4 + cq);
    float4 d0 = d4[a4];
    float4 d1 = d4[a4 + kHW / 4];
    float4 d2 = d4[a4 + 2 * (kHW / 4)];
    mx = fmaxf(mx, fmaxf(fmaxf(fmaxf(d0.x, d0.y), fmaxf(d0.z, d0.w)),
               fmaxf(fmaxf(fmaxf(d1.x, d1.y), fmaxf(d1.z, d1.w)),
                     fmaxf(fmaxf(d2.x, d2.y), fmaxf(d2.z, d2.w)))));
    if (!keep) {
      float4 u, s;
      u.x = ((d0.x + d1.x) + d2.x) / 3.0f;
      u.y = ((d0.y + d1.y) + d2.y) / 3.0f;
      u.z = ((d0.z + d1.z) + d2.z) / 3.0f;
      u.w = ((d0.w + d1.w) + d2.w) / 3.0f;
      s.x = ((d0.x / 255.0f + d1.x / 255.0f) + d2.x / 255.0f) / 3.0f;
      s.y = ((d0.y / 255.0f + d1.y / 255.0f) + d2.y / 255.0f) / 3.0f;
      s.z = ((d0.z / 255.0f + d1.z / 255.0f) + d2.z / 255.0f) / 3.0f;
      s.w = ((d0.w / 255.0f + d1.w / 255.0f) + d2.w / 255.0f) / 3.0f;
      out4[a4] = u;                 // gu in block b's own ch0 region
      out4[a4 + kHW / 4] = s;       // gs in block b's own ch1 region
    }
  }
  red[t] = mx;
  __syncthreads();
  for (int s = 128; s > 0; s >>= 1) {
    if (t < s) red[t] = fmaxf(red[t], red[t + s]);
    __syncthreads();
  }
  if (t == 0) Bmax[b] = red[0];
}

// ---------------- K3 mega: copy / 16-deep chain + RNG + radix select + apply ----------------
__global__ __launch_bounds__(256) void k3_mega(const float* __restrict__ img,
                                               float* __restrict__ out,
                                               const float* __restrict__ Bmax,
                                               uint32_t k1a, uint32_t k1b_,
                                               uint32_t k2a, uint32_t k2b) {
  __shared__ uint32_t hist[256];
  __shared__ uint32_t cand[64];
  __shared__ uint32_t sh[4];
  __shared__ uint32_t wtot[4];
  __shared__ float sacc;
  const int b = blockIdx.x, t = threadIdx.x;
  const int lane = t & 63, wv = t >> 6;
  const int bi = b >> 6, bj = b & 63;
  const int y0 = bi * 64, x0 = bj * 64;
  const float4* img4 = reinterpret_cast<const float4*>(img);
  float4* out4 = reinterpret_cast<float4*>(out);

  if (keep_block(k1a, k1b_, b)) {     // kept: pure copy (mask==1 everywhere)
    #pragma unroll
    for (int i = 0; i < 12; ++i) {
      int f = i * 256 + t;
      int ch = f >> 10, idx = f & 1023;
      int r = idx >> 4, cc = idx & 15;
      uint32_t a = (uint32_t)(y0 + r) * (kW / 4) + (uint32_t)(x0 / 4 + cc)
                 + (uint32_t)ch * (kHW / 4);
      out4[a] = img4[a];
    }
    return;
  }

  // ---- dropped block ----
  hist[t] = 0;
  if (t == 0) sh[3] = 0;
  __syncthreads();

  // wave 0: global flag + strict serial chain, 16-deep rolling pipeline
  if (wv == 0) {
    float m = 0.0f;
    #pragma unroll
    for (int i = 0; i < kNB / 64; ++i) m = fmaxf(m, Bmax[lane + i * 64]);
    #pragma unroll
    for (int d = 32; d >= 1; d >>= 1) m = fmaxf(m, __shfl_xor(m, d, 64));
    const bool flag = m > 1.0f;
    if (lane == 0) {
      const float4* base4 = out4 + (uint32_t)y0 * (kW / 4) + (uint32_t)(x0 / 4)
                          + (flag ? (uint32_t)(kHW / 4) : 0u);
      float4 buf[16];
      #pragma unroll
      for (int i = 0; i < 16; ++i) buf[i] = base4[i];       // row 0 in flight
      float acc = 0.0f;
      for (int row = 1; row < 64; ++row) {                  // strict order p=0..4095
        const float4* rp = base4 + (uint32_t)row * (kW / 4);
        #pragma unroll
        for (int i = 0; i < 16; ++i) {
          float4 v = buf[i];
          buf[i] = rp[i];                                   // row `row` in flight
          acc += v.x; acc += v.y; acc += v.z; acc += v.w;   // consume row `row-1`
        }
      }
      #pragma unroll
      for (int i = 0; i < 16; ++i) {
        float4 v = buf[i];
        acc += v.x; acc += v.y; acc += v.z; acc += v.w;     // row 63
      }
      sacc = acc;
    }
  }

  // all threads: reg-resident noise in apply order + level-1 histogram
  const int row0 = t >> 4, cq = t & 15;
  const uint32_t base = (uint32_t)b * (uint32_t)kBB;
  uint32_t v[4][4];
  #pragma unroll
  for (int it = 0; it < 4; ++it) {
    uint32_t p = (uint32_t)((it * 16 + row0) * 64 + cq * 4);
    #pragma unroll
    for (int j = 0; j < 4; ++j) v[it][j] = rbits(k2a, k2b, base + p + j) >> 9;
  }
  #pragma unroll
  for (int it = 0; it < 4; ++it)
    #pragma unroll
    for (int j = 0; j < 4; ++j) atomicAdd(&hist[v[it][j] >> 15], 1u);
  __syncthreads();   // chain done, hist complete

  int nz;
  {
    float sv = sacc;                 // == avg_depth*4096 bit-exactly (pow2 scalings)
    nz = (int)rintf(sv);             // round-half-even == jnp.round
    if (nz < 0) nz = 0;
    if (nz > kBB) nz = kBB;
  }

  if (nz == 0 || nz == kBB) {        // uniform: copy or fill (overwrites gray)
    const bool fill = (nz == kBB);
    const float4 g4v = make_float4(kGray, kGray, kGray, kGray);
    #pragma unroll
    for (int i = 0; i < 12; ++i) {
      int f = i * 256 + t;
      int ch = f >> 10, idx = f & 1023;
      int r = idx >> 4, cc = idx & 15;
      uint32_t a = (uint32_t)(y0 + r) * (kW / 4) + (uint32_t)(x0 / 4 + cc)
                 + (uint32_t)ch * (kHW / 4);
      out4[a] = fill ? g4v : img4[a];
    }
    return;
  }

  // level-1 wave scan (R11/R12/R13-validated)
  {
    uint32_t h = hist[t], sc = h;
    #pragma unroll
    for (int d = 1; d < 64; d <<= 1) {
      uint32_t vv = __shfl_up(sc, d, 64);
      if (lane >= d) sc += vv;
    }
    if (lane == 63) wtot[wv] = sc;
    __syncthreads();
    uint32_t pre = 0;
    for (int k = 0; k < wv; ++k) pre += wtot[k];
    uint32_t inc = sc + pre, exc = inc - h;
    if (inc >= (uint32_t)nz && exc < (uint32_t)nz) { sh[0] = (uint32_t)t; sh[1] = (uint32_t)nz - exc; }
    hist[t] = 0;
    __syncthreads();
  }
  const uint32_t B1 = sh[0], rr2 = sh[1];

  #pragma unroll
  for (int it = 0; it < 4; ++it)
    #pragma unroll
    for (int j = 0; j < 4; ++j) {
      uint32_t vv = v[it][j];
      if ((vv >> 15) == B1) atomicAdd(&hist[(vv >> 7) & 0xFFu], 1u);
    }
  __syncthreads();
  // level-2 wave scan
  {
    uint32_t h = hist[t], sc = h;
    #pragma unroll
    for (int d = 1; d < 64; d <<= 1) {
      uint32_t vv = __shfl_up(sc, d, 64);
      if (lane >= d) sc += vv;
    }
    if (lane == 63) wtot[wv] = sc;
    __syncthreads();
    uint32_t pre = 0;
    for (int k = 0; k < wv; ++k) pre += wtot[k];
    uint32_t inc = sc + pre, exc = inc - h;
    if (inc >= rr2 && exc < rr2) { sh[0] = (uint32_t)t; sh[1] = rr2 - exc; }
    __syncthreads();
  }
  const uint32_t pref16 = (B1 << 8) | sh[0];
  const uint32_t rr3 = sh[1];

  // level-3: collect full-prefix matches, rank by (low7, p)
  #pragma unroll
  for (int it = 0; it < 4; ++it)
    #pragma unroll
    for (int j = 0; j < 4; ++j) {
      uint32_t vv = v[it][j];
      if ((vv >> 7) == pref16) {
        uint32_t p = (uint32_t)((it * 16 + row0) * 64 + cq * 4 + j);
        uint32_t slot = atomicAdd(&sh[3], 1u);
        if (slot < 64u) cand[slot] = ((vv & 0x7Fu) << 12) | p;
      }
    }
  __syncthreads();
  const uint32_t m = sh[3] < 64u ? sh[3] : 64u;
  if (t < (int)m) {
    uint32_t key = cand[t], rank = 0;
    for (uint32_t q = 0; q < m; ++q) rank += (cand[q] < key) ? 1u : 0u;
    if (rank == rr3 - 1) sh[2] = key;
  }
  __syncthreads();
  const uint32_t T3 = sh[2];

  #pragma unroll
  for (int it = 0; it < 4; ++it) {
    uint32_t p = (uint32_t)((it * 16 + row0) * 64 + cq * 4);
    uint32_t kmask = 0;
    #pragma unroll
    for (int j = 0; j < 4; ++j) {
      uint32_t vv = v[it][j];
      uint32_t pre = vv >> 7;
      bool zero = (pre < pref16) ||
                  (pre == pref16 && ((((vv & 0x7Fu) << 12) | (p + j)) <= T3));
      if (!zero) kmask |= (1u << j);
    }
    uint32_t a4 = (uint32_t)(y0 + it * 16 + row0) * (kW / 4) + (uint32_t)(x0 / 4 + cq);
    #pragma unroll
    for (int ch = 0; ch < 3; ++ch) {
      uint32_t a = a4 + (uint32_t)ch * (kHW / 4);
      float4 vf = img4[a];
      float4 o;
      o.x = (kmask & 1u) ? vf.x : kGray;
      o.y = (kmask & 2u) ? vf.y : kGray;
      o.z = (kmask & 4u) ? vf.z : kGray;
      o.w = (kmask & 8u) ? vf.w : kGray;
      out4[a] = o;
    }
  }
}

// ---------------- host ----------------
extern "C" void kernel_launch(void* const* d_in, const int* in_sizes, int n_in,
                              void* d_out, int out_size, void* d_ws, size_t ws_size,
                              hipStream_t stream) {
  const float* img   = (const float*)d_in[0];
  const float* depth = (const float*)d_in[1];
  float* out = (float*)d_out;

  float* Bmax = (float*)d_ws;   // 8 KB

  uint32_t k1a, k1b_, k2a, k2b;
  tf2x32(0u, 42u, 0u, 0u, k1a, k1b_);     // split(key(42))[0]
  tf2x32(0u, 42u, 0u, 1u, k2a, k2b);      // split(key(42))[1]

  k1_depth<<<kNB, 256, 0, stream>>>(depth, out, Bmax, k1a, k1b_);
  k3_mega <<<kNB, 256, 0, stream>>>(img, out, Bmax, k1a, k1b_, k2a, k2b);
}

// Round 15
// 110.179 us; speedup vs baseline: 1.1553x; 1.1553x over previous
//
#include <hip/hip_runtime.h>
#include <stdint.h>

// ---------------- problem constants ----------------
static constexpr int kH  = 2048;
static constexpr int kW  = 4096;
static constexpr int kHW = kH * kW;            // per-channel pixels (2^23)
static constexpr int kNH = kH / 64;   // 32
static constexpr int kNW = kW / 64;   // 64
static constexpr int kNB = kNH * kNW; // 2048 blocks
static constexpr int kBB = 64 * 64;   // 4096 pixels / block
static constexpr float kGray = 128.0f;

// partitionable threefry (JAX >= 0.4.36 default) -- validated absmax 0.0 rounds 1-14
__host__ __device__ inline void tf2x32(uint32_t k0, uint32_t k1,
                                       uint32_t x0, uint32_t x1,
                                       uint32_t& o0, uint32_t& o1) {
  uint32_t ks2 = 0x1BD11BDAu ^ k0 ^ k1;
  x0 += k0; x1 += k1;
#define ROTL(v, d) (((v) << (d)) | ((v) >> (32 - (d))))
#define RND(R) { x0 += x1; x1 = ROTL(x1, R); x1 ^= x0; }
  RND(13) RND(15) RND(26) RND(6)
  x0 += k1;  x1 += ks2 + 1u;
  RND(17) RND(29) RND(16) RND(24)
  x0 += ks2; x1 += k0 + 2u;
  RND(13) RND(15) RND(26) RND(6)
  x0 += k0;  x1 += k1 + 3u;
  RND(17) RND(29) RND(16) RND(24)
  x0 += k1;  x1 += ks2 + 4u;
  RND(13) RND(15) RND(26) RND(6)
  x0 += ks2; x1 += k0 + 5u;
  o0 = x0; o1 = x1;
#undef RND
#undef ROTL
}

__device__ inline uint32_t rbits(uint32_t ka, uint32_t kb, uint32_t idx) {
  uint32_t o0, o1;
  tf2x32(ka, kb, 0u, idx, o0, o1);
  return o0 ^ o1;
}

__device__ inline bool keep_block(uint32_t k1a, uint32_t k1b, int b) {
  uint32_t v = rbits(k1a, k1b, (uint32_t)b) >> 9;
  return v > 0x400000u;   // uniform > 0.5 exactly
}

// ---------------- K1: block max + UNSCALED gray only (no divides) ----------------
__global__ __launch_bounds__(256) void k1_depth(const float* __restrict__ depth,
                                                float* __restrict__ Gu,
                                                float* __restrict__ Bmax,
                                                uint32_t k1a, uint32_t k1b_) {
  __shared__ float red[256];
  const int b = blockIdx.x, t = threadIdx.x;
  const int bi = b >> 6, bj = b & 63;
  const int y0 = bi * 64, x0 = bj * 64;
  const bool keep = keep_block(k1a, k1b_, b);
  const float4* d4 = reinterpret_cast<const float4*>(depth);

  float mx = 0.0f;
  #pragma unroll
  for (int it = 0; it < 4; ++it) {
    int idx = it * 256 + t;
    int r = idx >> 4, cq = idx & 15;
    uint32_t a4 = (uint32_t)(y0 + r) * (kW / 4) + (uint32_t)(x0 / 4 + cq);
    float4 d0 = d4[a4];
    float4 d1 = d4[a4 + kHW / 4];
    float4 d2 = d4[a4 + 2 * (kHW / 4)];
    mx = fmaxf(mx, fmaxf(fmaxf(fmaxf(d0.x, d0.y), fmaxf(d0.z, d0.w)),
               fmaxf(fmaxf(fmaxf(d1.x, d1.y), fmaxf(d1.z, d1.w)),
                     fmaxf(fmaxf(d2.x, d2.y), fmaxf(d2.z, d2.w)))));
    if (!keep) {
      uint32_t p4 = (uint32_t)b * (kBB / 4) + (uint32_t)idx;   // linear layout
      float4 u;
      u.x = ((d0.x + d1.x) + d2.x) / 3.0f;
      u.y = ((d0.y + d1.y) + d2.y) / 3.0f;
      u.z = ((d0.z + d1.z) + d2.z) / 3.0f;
      u.w = ((d0.w + d1.w) + d2.w) / 3.0f;
      reinterpret_cast<float4*>(Gu)[p4] = u;
    }
  }
  red[t] = mx;
  __syncthreads();
  for (int s = 128; s > 0; s >>= 1) {
    if (t < s) red[t] = fmaxf(red[t], red[t + s]);
    __syncthreads();
  }
  if (t == 0) Bmax[b] = red[0];
}

// ---------------- kchain (R12 fast path + inline-gs slow path) ----------------
__global__ __launch_bounds__(64) void kchain(const float* __restrict__ Gu,
                                             const float* __restrict__ depth,
                                             const float* __restrict__ Bmax,
                                             float* __restrict__ S,
                                             uint32_t k1a, uint32_t k1b_) {
  const int w = blockIdx.x, lane = threadIdx.x;

  // global scale flag from Bmax (wave-wide max reduce)
  float m = 0.0f;
  #pragma unroll
  for (int i = 0; i < kNB / 64; ++i) m = fmaxf(m, Bmax[lane + i * 64]);
  #pragma unroll
  for (int d = 32; d >= 1; d >>= 1) m = fmaxf(m, __shfl_xor(m, d, 64));
  const bool flag = m > 1.0f;

  // dropped-rank -> block id (validated round-6/8/12 derivation)
  uint32_t bits = 0; int c = 0;
  #pragma unroll
  for (int j = 0; j < 32; ++j) {
    int b = lane * 32 + j;
    if (!keep_block(k1a, k1b_, b)) { bits |= (1u << j); ++c; }
  }
  int P = c;
  #pragma unroll
  for (int d = 1; d < 64; d <<= 1) {
    int v = __shfl_up(P, d, 64);
    if (lane >= d) P += v;
  }
  const int total = __shfl(P, 63, 64);
  P -= c;
  const int r0 = 2 * w, r1 = 2 * w + 1;
  int b0c = -1, b1c = -1;
  if (r0 >= P && r0 < P + c) {
    uint32_t bb = bits;
    for (int i = r0 - P; i > 0; --i) bb &= bb - 1;
    b0c = lane * 32 + __ffs(bb) - 1;
  }
  if (r1 >= P && r1 < P + c) {
    uint32_t bb = bits;
    for (int i = r1 - P; i > 0; --i) bb &= bb - 1;
    b1c = lane * 32 + __ffs(bb) - 1;
  }
  unsigned long long m0 = __ballot(b0c >= 0);
  unsigned long long m1 = __ballot(b1c >= 0);
  const int blk0 = (r0 < total && m0) ? __shfl(b0c, (int)(__ffsll(m0) - 1), 64) : -1;
  const int blk1 = (r1 < total && m1) ? __shfl(b1c, (int)(__ffsll(m1) - 1), 64) : -1;

  const int blk = (lane == 0) ? blk0 : blk1;
  if (lane < 2 && blk >= 0) {
    float acc = 0.0f;
    if (!flag) {
      // FAST path (R12-validated): linear gu read, 32-deep register pipeline
      const float4* g4 = reinterpret_cast<const float4*>(Gu) + (uint32_t)blk * (kBB / 4);
      float4 buf[32];
      #pragma unroll
      for (int i = 0; i < 32; ++i) buf[i] = g4[i];
      uint32_t gp = 32;
      for (int outer = 0; outer < 31; ++outer) {
        #pragma unroll
        for (int i = 0; i < 32; ++i) {
          float4 v = buf[i];
          buf[i] = g4[gp + i];
          acc += v.x; acc += v.y; acc += v.z; acc += v.w;   // strict order p=0..4095
        }
        gp += 32;
      }
      #pragma unroll
      for (int i = 0; i < 32; ++i) {
        float4 v = buf[i];
        acc += v.x; acc += v.y; acc += v.z; acc += v.w;
      }
    } else {
      // SLOW path (flag==true; correctness-only): gs recomputed inline from depth,
      // identical f32 expression and strict p=0..4095 order as the old stored gs.
      const int bbi = blk >> 6, bbj = blk & 63;
      const float4* dbase = reinterpret_cast<const float4*>(depth)
                          + (uint32_t)(bbi * 64) * (kW / 4) + (uint32_t)(bbj * 16);
      for (int row = 0; row < 64; ++row) {
        const float4* rp = dbase + (uint32_t)row * (kW / 4);
        for (int cq = 0; cq < 16; ++cq) {
          float4 d0 = rp[cq];
          float4 d1 = rp[cq + kHW / 4];
          float4 d2 = rp[cq + 2 * (kHW / 4)];
          acc += ((d0.x / 255.0f + d1.x / 255.0f) + d2.x / 255.0f) / 3.0f;
          acc += ((d0.y / 255.0f + d1.y / 255.0f) + d2.y / 255.0f) / 3.0f;
          acc += ((d0.z / 255.0f + d1.z / 255.0f) + d2.z / 255.0f) / 3.0f;
          acc += ((d0.w / 255.0f + d1.w / 255.0f) + d2.w / 255.0f) / 3.0f;
        }
      }
    }
    S[blk] = acc;
  }
}

// ---------------- K3 fused (R12-validated): kept copy / dropped fill-copy-heavy ----------------
__global__ __launch_bounds__(256) void k3_fused(const float* __restrict__ img,
                                                float* __restrict__ out,
                                                const float* __restrict__ S,
                                                uint32_t k1a, uint32_t k1b_,
                                                uint32_t k2a, uint32_t k2b) {
  __shared__ uint32_t hist[256];
  __shared__ uint32_t cand[64];
  __shared__ uint32_t sh[4];
  __shared__ uint32_t wtot[4];
  const int b = blockIdx.x, t = threadIdx.x;
  const int lane = t & 63, wv = t >> 6;
  const int bi = b >> 6, bj = b & 63;
  const int y0 = bi * 64, x0 = bj * 64;
  const float4* img4 = reinterpret_cast<const float4*>(img);
  float4* out4 = reinterpret_cast<float4*>(out);

  int nz;
  if (keep_block(k1a, k1b_, b)) {
    nz = 0;
  } else {
    float sv = S[b];                 // == avg_depth*4096 bit-exactly (pow2 scalings)
    nz = (int)rintf(sv);             // round-half-even == jnp.round
    if (nz < 0) nz = 0;
    if (nz > kBB) nz = kBB;
  }
  const int row0 = t >> 4, cq = t & 15;

  if (nz == 0 || nz == kBB) {        // uniform: copy or fill
    const bool fill = (nz == kBB);
    const float4 g4v = make_float4(kGray, kGray, kGray, kGray);
    #pragma unroll
    for (int i = 0; i < 12; ++i) {
      int f = i * 256 + t;
      int ch = f >> 10, idx = f & 1023;
      int r = idx >> 4, cc = idx & 15;
      uint32_t a = (uint32_t)(y0 + r) * (kW / 4) + (uint32_t)(x0 / 4 + cc)
                 + (uint32_t)ch * (kHW / 4);
      out4[a] = fill ? g4v : img4[a];
    }
    return;
  }

  // heavy: reg-resident noise + 3-level radix select (wave scans; validated)
  const uint32_t base = (uint32_t)b * (uint32_t)kBB;
  uint32_t v[4][4];
  #pragma unroll
  for (int it = 0; it < 4; ++it) {
    uint32_t p = (uint32_t)((it * 16 + row0) * 64 + cq * 4);
    #pragma unroll
    for (int j = 0; j < 4; ++j) v[it][j] = rbits(k2a, k2b, base + p + j) >> 9;
  }

  hist[t] = 0;
  if (t == 0) sh[3] = 0;
  __syncthreads();
  #pragma unroll
  for (int it = 0; it < 4; ++it)
    #pragma unroll
    for (int j = 0; j < 4; ++j) atomicAdd(&hist[v[it][j] >> 15], 1u);
  __syncthreads();
  // level-1 wave scan
  {
    uint32_t h = hist[t], sc = h;
    #pragma unroll
    for (int d = 1; d < 64; d <<= 1) {
      uint32_t vv = __shfl_up(sc, d, 64);
      if (lane >= d) sc += vv;
    }
    if (lane == 63) wtot[wv] = sc;
    __syncthreads();
    uint32_t pre = 0;
    for (int k = 0; k < wv; ++k) pre += wtot[k];
    uint32_t inc = sc + pre, exc = inc - h;
    if (inc >= (uint32_t)nz && exc < (uint32_t)nz) { sh[0] = (uint32_t)t; sh[1] = (uint32_t)nz - exc; }
    hist[t] = 0;
    __syncthreads();
  }
  const uint32_t B1 = sh[0], rr2 = sh[1];

  #pragma unroll
  for (int it = 0; it < 4; ++it)
    #pragma unroll
    for (int j = 0; j < 4; ++j) {
      uint32_t vv = v[it][j];
      if ((vv >> 15) == B1) atomicAdd(&hist[(vv >> 7) & 0xFFu], 1u);
    }
  __syncthreads();
  // level-2 wave scan
  {
    uint32_t h = hist[t], sc = h;
    #pragma unroll
    for (int d = 1; d < 64; d <<= 1) {
      uint32_t vv = __shfl_up(sc, d, 64);
      if (lane >= d) sc += vv;
    }
    if (lane == 63) wtot[wv] = sc;
    __syncthreads();
    uint32_t pre = 0;
    for (int k = 0; k < wv; ++k) pre += wtot[k];
    uint32_t inc = sc + pre, exc = inc - h;
    if (inc >= rr2 && exc < rr2) { sh[0] = (uint32_t)t; sh[1] = rr2 - exc; }
    __syncthreads();
  }
  const uint32_t pref16 = (B1 << 8) | sh[0];
  const uint32_t rr3 = sh[1];

  // level-3: collect full-prefix matches, rank by (low7, p)
  #pragma unroll
  for (int it = 0; it < 4; ++it)
    #pragma unroll
    for (int j = 0; j < 4; ++j) {
      uint32_t vv = v[it][j];
      if ((vv >> 7) == pref16) {
        uint32_t p = (uint32_t)((it * 16 + row0) * 64 + cq * 4 + j);
        uint32_t slot = atomicAdd(&sh[3], 1u);
        if (slot < 64u) cand[slot] = ((vv & 0x7Fu) << 12) | p;
      }
    }
  __syncthreads();
  const uint32_t m = sh[3] < 64u ? sh[3] : 64u;
  if (t < (int)m) {
    uint32_t key = cand[t], rank = 0;
    for (uint32_t q = 0; q < m; ++q) rank += (cand[q] < key) ? 1u : 0u;
    if (rank == rr3 - 1) sh[2] = key;
  }
  __syncthreads();
  const uint32_t T3 = sh[2];

  #pragma unroll
  for (int it = 0; it < 4; ++it) {
    uint32_t p = (uint32_t)((it * 16 + row0) * 64 + cq * 4);
    uint32_t kmask = 0;
    #pragma unroll
    for (int j = 0; j < 4; ++j) {
      uint32_t vv = v[it][j];
      uint32_t pre = vv >> 7;
      bool zero = (pre < pref16) ||
                  (pre == pref16 && ((((vv & 0x7Fu) << 12) | (p + j)) <= T3));
      if (!zero) kmask |= (1u << j);
    }
    uint32_t a4 = (uint32_t)(y0 + it * 16 + row0) * (kW / 4) + (uint32_t)(x0 / 4 + cq);
    #pragma unroll
    for (int ch = 0; ch < 3; ++ch) {
      uint32_t a = a4 + (uint32_t)ch * (kHW / 4);
      float4 vf = img4[a];
      float4 o;
      o.x = (kmask & 1u) ? vf.x : kGray;
      o.y = (kmask & 2u) ? vf.y : kGray;
      o.z = (kmask & 4u) ? vf.z : kGray;
      o.w = (kmask & 8u) ? vf.w : kGray;
      out4[a] = o;
    }
  }
}

// ---------------- host ----------------
extern "C" void kernel_launch(void* const* d_in, const int* in_sizes, int n_in,
                              void* d_out, int out_size, void* d_ws, size_t ws_size,
                              hipStream_t stream) {
  const float* img   = (const float*)d_in[0];
  const float* depth = (const float*)d_in[1];
  float* out = (float*)d_out;

  // gu scratch lives in d_out (32 MiB linear; fully overwritten by k3 afterwards)
  float* Gu = out;

  float* S    = (float*)d_ws;
  float* Bmax = S + kNB;

  uint32_t k1a, k1b_, k2a, k2b;
  tf2x32(0u, 42u, 0u, 0u, k1a, k1b_);     // split(key(42))[0]
  tf2x32(0u, 42u, 0u, 1u, k2a, k2b);      // split(key(42))[1]

  k1_depth<<<kNB, 256, 0, stream>>>(depth, Gu, Bmax, k1a, k1b_);
  kchain  <<<kNB / 2, 64, 0, stream>>>(Gu, depth, Bmax, S, k1a, k1b_);
  k3_fused<<<kNB, 256, 0, stream>>>(img, out, S, k1a, k1b_, k2a, k2b);
}